// Round 3
// baseline (384.388 us; speedup 1.0000x reference)
//
#include <hip/hip_runtime.h>

// RandomEqualize: PIL-style histogram equalization per (batch, channel).
// Input: float32 (64,3,512,512) with exact integer values in [0,255].
// N = 192 channels, P = 262144 pixels/channel.
//
// Pass A: histogram (per-block partial, no global atomics) + pack image to u8
// Pass B: reduce partials -> PIL LUT (float)
// Pass C: apply LUT reading the packed u8 image (L3-resident), write float

#define NBINS 256
#define BPC 32  // blocks per channel for hist/apply

// ---------------- Kernel A: histogram + pack ----------------
// 32 bank-strided sub-histogram copies: word (bin*32 + copy) -> bank = copy.
// copy = lane&31 guarantees each lane's ds_atomic hits its own bank.
__global__ __launch_bounds__(256) void eq_hist_pack_kernel(
    const float* __restrict__ in, unsigned int* __restrict__ phist,
    unsigned int* __restrict__ packed, int P, int bpc) {
    __shared__ unsigned int lh[NBINS * 32];  // 32 KB
    const int t = threadIdx.x;
    const int copy = t & 31;

    for (int i = t; i < NBINS * 32; i += 256) lh[i] = 0u;
    __syncthreads();

    const int chan = blockIdx.x / bpc;
    const int blk  = blockIdx.x % bpc;
    const int chunk = P / bpc;                 // 8192 pixels
    const size_t base = (size_t)chan * P + (size_t)blk * chunk;
    const float4* vin = (const float4*)(in + base);
    unsigned int* pout = packed + base / 4;    // 1 uint per 4 pixels
    const int nvec = chunk / 4;                // 2048

    for (int i = t; i < nvec; i += 256) {
        float4 v = vin[i];
        unsigned int ix = (unsigned int)min(max((int)v.x, 0), 255);
        unsigned int iy = (unsigned int)min(max((int)v.y, 0), 255);
        unsigned int iz = (unsigned int)min(max((int)v.z, 0), 255);
        unsigned int iw = (unsigned int)min(max((int)v.w, 0), 255);
        atomicAdd(&lh[ix * 32 + copy], 1u);
        atomicAdd(&lh[iy * 32 + copy], 1u);
        atomicAdd(&lh[iz * 32 + copy], 1u);
        atomicAdd(&lh[iw * 32 + copy], 1u);
        pout[i] = ix | (iy << 8) | (iz << 16) | (iw << 24);
    }
    __syncthreads();

    // Thread t owns bin t; staggered copy index keeps lanes on distinct banks.
    unsigned int s = 0;
    #pragma unroll
    for (int c = 0; c < 32; ++c)
        s += lh[t * 32 + ((t + c) & 31)];
    phist[(size_t)blockIdx.x * NBINS + t] = s;   // partial, no atomics
}

// ---------------- Kernel B: reduce partials + PIL LUT ----------------
__global__ __launch_bounds__(256) void eq_lut_kernel(
    const unsigned int* __restrict__ phist, float* __restrict__ glut,
    int P, int bpc) {
    __shared__ unsigned int s[NBINS];
    __shared__ int sidx[NBINS];
    const int t = threadIdx.x;
    const int chan = blockIdx.x;

    unsigned int h = 0;
    const unsigned int* pbase = phist + (size_t)chan * bpc * NBINS;
    for (int b = 0; b < bpc; ++b) h += pbase[b * NBINS + t];
    s[t] = h;
    sidx[t] = (h != 0u) ? t : -1;
    __syncthreads();

    // max-reduce: last nonzero bin index
    for (int off = 128; off > 0; off >>= 1) {
        if (t < off) sidx[t] = max(sidx[t], sidx[t + off]);
        __syncthreads();
    }
    const int last_idx = sidx[0];
    const unsigned int last_val = s[last_idx];
    const int step = (P - (int)last_val) / 255;

    // Hillis-Steele inclusive scan
    for (int off = 1; off < NBINS; off <<= 1) {
        unsigned int val = (t >= off) ? s[t - off] : 0u;
        __syncthreads();
        s[t] += val;
        __syncthreads();
    }

    float lv;
    if (step == 0) {
        lv = (float)t;  // pass-through: identity LUT
    } else {
        int cs_prev = (t == 0) ? 0 : (int)s[t - 1];
        int l = (cs_prev + (step >> 1)) / step;
        l = min(max(l, 0), 255);
        lv = (float)l;
    }
    glut[chan * NBINS + t] = lv;
}

// ---------------- Kernel C: apply LUT from packed u8 ----------------
__global__ __launch_bounds__(256) void eq_apply_kernel(
    const unsigned int* __restrict__ packed, const float* __restrict__ glut,
    float* __restrict__ out, int P, int bpc) {
    __shared__ float slut[NBINS];
    const int t = threadIdx.x;
    const int chan = blockIdx.x / bpc;
    const int blk  = blockIdx.x % bpc;

    slut[t] = glut[chan * NBINS + t];
    __syncthreads();

    const int chunk = P / bpc;                   // 8192 px
    const size_t base = (size_t)chan * P + (size_t)blk * chunk;
    const uint4* pin = (const uint4*)(packed + base / 4);  // 16 px / uint4
    float4* vout = (float4*)(out + base);
    const int nq = chunk / 16;                   // 512 uint4 per block

    for (int i = t; i < nq; i += 256) {
        uint4 p = pin[i];
        float4 r0, r1, r2, r3;
        r0.x = slut[p.x & 255u];  r0.y = slut[(p.x >> 8) & 255u];
        r0.z = slut[(p.x >> 16) & 255u];  r0.w = slut[p.x >> 24];
        r1.x = slut[p.y & 255u];  r1.y = slut[(p.y >> 8) & 255u];
        r1.z = slut[(p.y >> 16) & 255u];  r1.w = slut[p.y >> 24];
        r2.x = slut[p.z & 255u];  r2.y = slut[(p.z >> 8) & 255u];
        r2.z = slut[(p.z >> 16) & 255u];  r2.w = slut[p.z >> 24];
        r3.x = slut[p.w & 255u];  r3.y = slut[(p.w >> 8) & 255u];
        r3.z = slut[(p.w >> 16) & 255u];  r3.w = slut[p.w >> 24];
        vout[i * 4 + 0] = r0;
        vout[i * 4 + 1] = r1;
        vout[i * 4 + 2] = r2;
        vout[i * 4 + 3] = r3;
    }
}

extern "C" void kernel_launch(void* const* d_in, const int* in_sizes, int n_in,
                              void* d_out, int out_size, void* d_ws, size_t ws_size,
                              hipStream_t stream) {
    const float* img = (const float*)d_in[0];
    float* out = (float*)d_out;

    const int P = 512 * 512;                 // pixels per channel
    const int total = in_sizes[0];           // 64*3*512*512
    const int N = total / P;                 // 192 channels

    // ws layout: packed u8 image | partial hists | LUTs
    unsigned int* packed = (unsigned int*)d_ws;                 // total/4 uints
    unsigned int* phist  = (unsigned int*)((char*)d_ws + (size_t)total);
    float* glut = (float*)((char*)phist +
                           (size_t)N * BPC * NBINS * sizeof(unsigned int));

    eq_hist_pack_kernel<<<N * BPC, 256, 0, stream>>>(img, phist, packed, P, BPC);
    eq_lut_kernel<<<N, 256, 0, stream>>>(phist, glut, P, BPC);
    eq_apply_kernel<<<N * BPC, 256, 0, stream>>>(packed, glut, out, P, BPC);
}

// Round 5
// 367.565 us; speedup vs baseline: 1.0458x; 1.0458x over previous
//
#include <hip/hip_runtime.h>

// RandomEqualize: PIL-style histogram equalization per (batch, channel).
// Input: float32 (64,3,512,512) with exact integer values in [0,255].
// N = 192 channels, P = 262144 pixels/channel.
//
// Pass A: per-block partial histograms (bank-strided LDS, no global atomics)
// Pass B: reduce partials -> PIL LUT (float)
// Pass C: apply LUT (32x bank-replicated LUT in LDS -> conflict-free gather),
//         reading the (L3-resident) float input, non-temporal output stores.

#define NBINS 256
#define BPC 32  // blocks per channel for hist/apply

typedef float vfloat4 __attribute__((ext_vector_type(4)));  // native vec for NT store

// ---------------- Kernel A: histogram ----------------
// 32 bank-strided sub-histogram copies: word (bin*32 + copy) -> bank = copy.
// copy = lane&31 guarantees each lane's ds_atomic hits its own bank.
__global__ __launch_bounds__(256) void eq_hist_kernel(
    const float* __restrict__ in, unsigned int* __restrict__ phist,
    int P, int bpc) {
    __shared__ unsigned int lh[NBINS * 32];  // 32 KB
    const int t = threadIdx.x;
    const int copy = t & 31;

    for (int i = t; i < NBINS * 32; i += 256) lh[i] = 0u;
    __syncthreads();

    const int chan = blockIdx.x / bpc;
    const int blk  = blockIdx.x % bpc;
    const int chunk = P / bpc;                 // 8192 pixels
    const size_t base = (size_t)chan * P + (size_t)blk * chunk;
    const float4* vin = (const float4*)(in + base);
    const int nvec = chunk / 4;                // 2048

    for (int i = t; i < nvec; i += 256) {
        float4 v = vin[i];
        int ix = min(max((int)v.x, 0), 255);
        int iy = min(max((int)v.y, 0), 255);
        int iz = min(max((int)v.z, 0), 255);
        int iw = min(max((int)v.w, 0), 255);
        atomicAdd(&lh[ix * 32 + copy], 1u);
        atomicAdd(&lh[iy * 32 + copy], 1u);
        atomicAdd(&lh[iz * 32 + copy], 1u);
        atomicAdd(&lh[iw * 32 + copy], 1u);
    }
    __syncthreads();

    // Thread t owns bin t; staggered copy index keeps lanes on distinct banks.
    unsigned int s = 0;
    #pragma unroll
    for (int c = 0; c < 32; ++c)
        s += lh[t * 32 + ((t + c) & 31)];
    phist[(size_t)blockIdx.x * NBINS + t] = s;   // partial, no atomics
}

// ---------------- Kernel B: reduce partials + PIL LUT ----------------
__global__ __launch_bounds__(256) void eq_lut_kernel(
    const unsigned int* __restrict__ phist, float* __restrict__ glut,
    int P, int bpc) {
    __shared__ unsigned int s[NBINS];
    __shared__ int sidx[NBINS];
    const int t = threadIdx.x;
    const int chan = blockIdx.x;

    unsigned int h = 0;
    const unsigned int* pbase = phist + (size_t)chan * bpc * NBINS;
    for (int b = 0; b < bpc; ++b) h += pbase[b * NBINS + t];
    s[t] = h;
    sidx[t] = (h != 0u) ? t : -1;
    __syncthreads();

    // max-reduce: last nonzero bin index
    for (int off = 128; off > 0; off >>= 1) {
        if (t < off) sidx[t] = max(sidx[t], sidx[t + off]);
        __syncthreads();
    }
    const int last_idx = sidx[0];
    const unsigned int last_val = s[last_idx];
    const int step = (P - (int)last_val) / 255;

    // Hillis-Steele inclusive scan
    for (int off = 1; off < NBINS; off <<= 1) {
        unsigned int val = (t >= off) ? s[t - off] : 0u;
        __syncthreads();
        s[t] += val;
        __syncthreads();
    }

    float lv;
    if (step == 0) {
        lv = (float)t;  // pass-through: identity LUT
    } else {
        int cs_prev = (t == 0) ? 0 : (int)s[t - 1];
        int l = (cs_prev + (step >> 1)) / step;
        l = min(max(l, 0), 255);
        lv = (float)l;
    }
    glut[chan * NBINS + t] = lv;
}

// ---------------- Kernel C: apply LUT ----------------
// LUT replicated 32x, bank-strided: word (bin*32 + copy) -> bank = copy =
// lane&31, so every gather is conflict-free regardless of the bin value.
__global__ __launch_bounds__(256) void eq_apply_kernel(
    const float* __restrict__ in, const float* __restrict__ glut,
    float* __restrict__ out, int P, int bpc) {
    __shared__ float slut[NBINS * 32];  // 32 KB
    const int t = threadIdx.x;
    const int copy = t & 31;
    const int chan = blockIdx.x / bpc;
    const int blk  = blockIdx.x % bpc;

    const float lv = glut[chan * NBINS + t];  // thread t owns bin t
    #pragma unroll
    for (int c = 0; c < 32; ++c)
        slut[t * 32 + ((t + c) & 31)] = lv;   // bank (t+c)&31: 2-way, free
    __syncthreads();

    const int chunk = P / bpc;
    const size_t base = (size_t)chan * P + (size_t)blk * chunk;
    const float4* vin = (const float4*)(in + base);
    vfloat4* vout = (vfloat4*)(out + base);
    const int nvec = chunk / 4;

    for (int i = t; i < nvec; i += 256) {
        float4 v = vin[i];
        vfloat4 r;
        r.x = slut[min(max((int)v.x, 0), 255) * 32 + copy];
        r.y = slut[min(max((int)v.y, 0), 255) * 32 + copy];
        r.z = slut[min(max((int)v.z, 0), 255) * 32 + copy];
        r.w = slut[min(max((int)v.w, 0), 255) * 32 + copy];
        __builtin_nontemporal_store(r, &vout[i]);  // don't evict input from L3
    }
}

extern "C" void kernel_launch(void* const* d_in, const int* in_sizes, int n_in,
                              void* d_out, int out_size, void* d_ws, size_t ws_size,
                              hipStream_t stream) {
    const float* img = (const float*)d_in[0];
    float* out = (float*)d_out;

    const int P = 512 * 512;                 // pixels per channel
    const int total = in_sizes[0];           // 64*3*512*512
    const int N = total / P;                 // 192 channels

    // ws layout: partial hists | LUTs
    unsigned int* phist = (unsigned int*)d_ws;
    float* glut = (float*)((char*)d_ws +
                           (size_t)N * BPC * NBINS * sizeof(unsigned int));

    eq_hist_kernel<<<N * BPC, 256, 0, stream>>>(img, phist, P, BPC);
    eq_lut_kernel<<<N, 256, 0, stream>>>(phist, glut, P, BPC);
    eq_apply_kernel<<<N * BPC, 256, 0, stream>>>(img, glut, out, P, BPC);
}